// Round 2
// baseline (1216.536 us; speedup 1.0000x reference)
//
#include <hip/hip_runtime.h>
#include <hip/hip_bf16.h>

typedef _Float16 f16;
typedef _Float16 f16x8 __attribute__((ext_vector_type(8)));
typedef float f32x4 __attribute__((ext_vector_type(4)));

#define NBATCH 128
#define NTIME  128
#define NKIN   512
#define NUNITS 512
#define NGATE  2048

static __device__ __forceinline__ float sigmoidf_(float x) {
    return 1.0f / (1.0f + __expf(-x));
}
static __device__ __forceinline__ float tanhf_(float x) {
    float t = __expf(-2.0f * fabsf(x));
    float r = (1.0f - t) / (1.0f + t);
    return copysignf(r, x);
}

static __device__ __forceinline__ f16x8 pack8(float4 a, float4 b) {
    f16x8 r;
    r[0] = (f16)a.x; r[1] = (f16)a.y; r[2] = (f16)a.z; r[3] = (f16)a.w;
    r[4] = (f16)b.x; r[5] = (f16)b.y; r[6] = (f16)b.z; r[7] = (f16)b.w;
    return r;
}

// ---------------- transpose: f32 in[512][2048] -> f16 out[2048][512] ----------------
__global__ __launch_bounds__(256)
void k_transpose(const float* __restrict__ in, f16* __restrict__ out) {
    __shared__ f16 tile[64][72];
    const int c0 = blockIdx.x * 64;
    const int r0 = blockIdx.y * 64;
    const int tid = threadIdx.x;
    {
        const int lr = tid >> 2;
        const int lc = (tid & 3) << 4;
        const float* src = in + (size_t)(r0 + lr) * NGATE + c0 + lc;
        float4 v0 = ((const float4*)src)[0];
        float4 v1 = ((const float4*)src)[1];
        float4 v2 = ((const float4*)src)[2];
        float4 v3 = ((const float4*)src)[3];
        *(f16x8*)&tile[lr][lc]     = pack8(v0, v1);
        *(f16x8*)&tile[lr][lc + 8] = pack8(v2, v3);
    }
    __syncthreads();
    {
        const int lc = tid >> 2;
        const int lr = (tid & 3) << 4;
        f16x8 a, b;
#pragma unroll
        for (int i = 0; i < 8; ++i) a[i] = tile[lr + i][lc];
#pragma unroll
        for (int i = 0; i < 8; ++i) b[i] = tile[lr + 8 + i][lc];
        f16* dst = out + (size_t)(c0 + lc) * NKIN + r0 + lr;
        *(f16x8*)dst       = a;
        *(f16x8*)(dst + 8) = b;
    }
}

// ---------------- projection: xz[t][b][g] = x[b][t][:] @ W[:][g] + bias[g] ----------------
// BM=128 (all b for one t), BN=128, BK=32. 4 waves 2x2, wave tile 64x64 (acc 4x4).
// XCD-swizzled block id for x-slab L2 locality (2048 blocks % 8 == 0 -> bijective).
__global__ __launch_bounds__(256)
void k_proj(const float* __restrict__ x, const f16* __restrict__ Wt,
            const float* __restrict__ bias, f16* __restrict__ xz) {
    __shared__ f16 As[128][40];
    __shared__ f16 Bs[128][40];
    const int bid = blockIdx.y * gridDim.x + blockIdx.x;   // 0..2047
    const int swz = (bid & 7) * 256 + (bid >> 3);          // contiguous chunk per XCD
    const int nb = swz & 15;       // 16 n-blocks
    const int tb = swz >> 4;       // 128 t-blocks
    const int n0 = nb * 128;
    const int tid  = threadIdx.x;
    const int lane = tid & 63;
    const int wid  = tid >> 6;
    const int wm = (wid >> 1) * 64;
    const int wn = (wid & 1) * 64;
    const int lm = lane & 15;
    const int lg = lane >> 4;

    f32x4 acc[4][4];
#pragma unroll
    for (int mi = 0; mi < 4; ++mi)
#pragma unroll
        for (int ni = 0; ni < 4; ++ni)
#pragma unroll
            for (int i = 0; i < 4; ++i) acc[mi][ni][i] = 0.0f;

    for (int kt = 0; kt < NKIN; kt += 32) {
        // stage A: rows are batch b, data from x[b][tb][kt..kt+32)
        {
            const int brow = tid >> 1;
            const int kq   = (tid & 1) << 4;
            const float* src = x + ((size_t)brow * NTIME + tb) * NKIN + kt + kq;
            float4 v0 = ((const float4*)src)[0];
            float4 v1 = ((const float4*)src)[1];
            float4 v2 = ((const float4*)src)[2];
            float4 v3 = ((const float4*)src)[3];
            *(f16x8*)&As[brow][kq]     = pack8(v0, v1);
            *(f16x8*)&As[brow][kq + 8] = pack8(v2, v3);
        }
        // stage B: 128 gate-cols x 32 k from Wt
        {
            const int nrow = tid >> 1;
            const int kq   = (tid & 1) << 4;
            const f16* src = Wt + (size_t)(n0 + nrow) * NKIN + kt + kq;
            *(f16x8*)&Bs[nrow][kq]     = *(const f16x8*)src;
            *(f16x8*)&Bs[nrow][kq + 8] = *(const f16x8*)(src + 8);
        }
        __syncthreads();
        f16x8 a[4], b[4];
#pragma unroll
        for (int mi = 0; mi < 4; ++mi)
            a[mi] = *(const f16x8*)&As[wm + mi * 16 + lm][lg * 8];
#pragma unroll
        for (int ni = 0; ni < 4; ++ni)
            b[ni] = *(const f16x8*)&Bs[wn + ni * 16 + lm][lg * 8];
#pragma unroll
        for (int mi = 0; mi < 4; ++mi)
#pragma unroll
            for (int ni = 0; ni < 4; ++ni)
                acc[mi][ni] = __builtin_amdgcn_mfma_f32_16x16x32_f16(a[mi], b[ni], acc[mi][ni], 0, 0, 0);
        __syncthreads();
    }
#pragma unroll
    for (int mi = 0; mi < 4; ++mi) {
#pragma unroll
        for (int ni = 0; ni < 4; ++ni) {
            const int col = n0 + wn + ni * 16 + lm;
            const float bv = bias[col];
#pragma unroll
            for (int i = 0; i < 4; ++i) {
                const int brow = wm + mi * 16 + lg * 4 + i;
                xz[((size_t)tb * NBATCH + brow) * NGATE + col] = (f16)(acc[mi][ni][i] + bv);
            }
        }
    }
}

// ---------------- persistent LSTM: all 128 timesteps in one launch ----------------
// 256 blocks (one per CU; 87.5 KB LDS forces 1/CU). bg = bid&7 (8 batch-groups, one
// per XCD under round-robin heuristic), ug = bid>>3 (32 unit-groups).
// 8 INDEPENDENT 32-block groups; per-step device-scope barrier per group.
// U columns in LDS once; cell state c in registers for all steps.
__global__ __launch_bounds__(256)
void k_lstm(const f16* __restrict__ xz, const f16* __restrict__ Ut,
            f16* __restrict__ h0, f16* __restrict__ h1,
            float* __restrict__ out, int* __restrict__ barrier_cnt) {
    __shared__ f16 Us[64][520];       // 64 gate-cols x 512 k (66.5 KB), persistent
    __shared__ f16 As[16][520];       // h rows staging (16.6 KB)
    __shared__ float zs[4][16][17];   // gate exchange
    const int bid = blockIdx.x;
    const int bg = bid & 7;
    const int ug = bid >> 3;
    const int r0 = bg * 16;
    const int u0 = ug * 16;
    const int tid  = threadIdx.x;
    const int lane = tid & 63;
    const int g    = tid >> 6;        // wave id == gate
    const int lm = lane & 15;
    const int lg = lane >> 4;

    // one-time: load this block's 64 U gate-columns into LDS
    {
        const int c  = tid >> 2;
        const int kq = (tid & 3) << 7;
        const int gcol = (c >> 4) * NUNITS + u0 + (c & 15);
        const f16* src = Ut + (size_t)gcol * NUNITS + kq;
#pragma unroll
        for (int q = 0; q < 16; ++q)
            *(f16x8*)&Us[c][kq + q * 8] = *(const f16x8*)(src + q * 8);
    }
    const int srow = tid >> 4;        // state-update row 0..15
    const int suu  = tid & 15;        // state-update unit 0..15
    const int gidx = (r0 + srow) * NUNITS + u0 + suu;
    float c_reg = 0.0f;
    int* cnt = barrier_cnt + bg * 64; // 256B-spaced counters
    __syncthreads();

    for (int t = 0; t < NTIME; ++t) {
        const f16* hin = (t & 1) ? h1 : h0;
        f16*      hout = (t & 1) ? h0 : h1;
        // acc init from xz[t][b][gatecol] (ready since proj finished; hides under staging)
        f32x4 acc;
        {
            const int colg = g * NUNITS + u0 + lm;
            const f16* xzp = xz + ((size_t)t * NBATCH + r0 + lg * 4) * NGATE + colg;
#pragma unroll
            for (int i = 0; i < 4; ++i)
                acc[i] = (float)xzp[(size_t)i * NGATE];
        }
        // stage h rows (16 x 512)
        {
            const int row = tid >> 4;
            const int kq  = (tid & 15) << 5;
            const f16* src = hin + (size_t)(r0 + row) * NUNITS + kq;
#pragma unroll
            for (int q = 0; q < 4; ++q)
                *(f16x8*)&As[row][kq + q * 8] = *(const f16x8*)(src + q * 8);
        }
        __syncthreads();
#pragma unroll
        for (int kk = 0; kk < NUNITS; kk += 32) {
            f16x8 a = *(const f16x8*)&As[lm][kk + lg * 8];
            f16x8 b = *(const f16x8*)&Us[g * 16 + lm][kk + lg * 8];
            acc = __builtin_amdgcn_mfma_f32_16x16x32_f16(a, b, acc, 0, 0, 0);
        }
#pragma unroll
        for (int i = 0; i < 4; ++i)
            zs[g][lg * 4 + i][lm] = acc[i];
        __syncthreads();
        const float zi = zs[0][srow][suu];
        const float zf = zs[1][srow][suu];
        const float zg = zs[2][srow][suu];
        const float zo = zs[3][srow][suu];
        const float iv = sigmoidf_(zi);
        const float fv = sigmoidf_(zf);
        const float gv = tanhf_(zg);
        const float ov = sigmoidf_(zo);
        c_reg = fv * c_reg + iv * gv;
        const float hn = ov * tanhf_(c_reg);
        hout[gidx] = (f16)hn;
        if (t == NTIME - 1) {
            out[gidx]          = hn;    // last_h
            out[65536 + gidx]  = hn;    // state_h
            out[131072 + gidx] = c_reg; // state_c
        } else {
            // group barrier: release makes h stores visible (L2 writeback),
            // acquire invalidates stale L1/L2 before next step's h reads.
            __syncthreads();  // all h stores drained (vmcnt(0) before s_barrier)
            if (tid == 0) {
                __hip_atomic_fetch_add(cnt, 1, __ATOMIC_ACQ_REL, __HIP_MEMORY_SCOPE_AGENT);
                const int target = 32 * (t + 1);
                while (__hip_atomic_load(cnt, __ATOMIC_RELAXED, __HIP_MEMORY_SCOPE_AGENT) < target)
                    __builtin_amdgcn_s_sleep(2);
                (void)__hip_atomic_load(cnt, __ATOMIC_ACQUIRE, __HIP_MEMORY_SCOPE_AGENT);
            }
            __syncthreads();
        }
    }
}

extern "C" void kernel_launch(void* const* d_in, const int* in_sizes, int n_in,
                              void* d_out, int out_size, void* d_ws, size_t ws_size,
                              hipStream_t stream) {
    const float* x    = (const float*)d_in[0];
    const float* W    = (const float*)d_in[1];
    const float* U    = (const float*)d_in[2];
    const float* bias = (const float*)d_in[3];
    float* out = (float*)d_out;
    char* ws = (char*)d_ws;

    size_t off = 0;
    f16* Wt = (f16*)(ws + off); off += (size_t)NGATE * NKIN * 2;
    f16* Ut = (f16*)(ws + off); off += (size_t)NGATE * NUNITS * 2;
    f16* xz = (f16*)(ws + off); off += (size_t)NTIME * NBATCH * NGATE * 2;  // [t][b][g]
    f16* h0 = (f16*)(ws + off); off += (size_t)NBATCH * NUNITS * 2;
    f16* h1 = (f16*)(ws + off); off += (size_t)NBATCH * NUNITS * 2;
    int* cnt = (int*)(ws + off); off += 8 * 64 * sizeof(int);
    if (ws_size < off) return;

    hipMemsetAsync(h0,  0, (size_t)NBATCH * NUNITS * 2, stream);
    hipMemsetAsync(cnt, 0, 8 * 64 * sizeof(int), stream);

    k_transpose<<<dim3(32, 8), 256, 0, stream>>>(W, Wt);
    k_transpose<<<dim3(32, 8), 256, 0, stream>>>(U, Ut);
    k_proj<<<dim3(16, 128), 256, 0, stream>>>(x, Wt, bias, xz);
    k_lstm<<<dim3(256), 256, 0, stream>>>(xz, Ut, h0, h1, out, cnt);
}

// Round 3
// 472.205 us; speedup vs baseline: 2.5763x; 2.5763x over previous
//
#include <hip/hip_runtime.h>
#include <hip/hip_bf16.h>

typedef _Float16 f16;
typedef _Float16 f16x8 __attribute__((ext_vector_type(8)));
typedef float f32x4 __attribute__((ext_vector_type(4)));

#define NBATCH 128
#define NTIME  128
#define NKIN   512
#define NUNITS 512
#define NGATE  2048

#define GROUPS 16   // batch groups (8 rows each)
#define BLKPG  16   // blocks per group (32 unit-cols each)
#define GROWS  8    // batch rows per group

static __device__ __forceinline__ float sigmoidf_(float x) {
    return 1.0f / (1.0f + __expf(-x));
}
static __device__ __forceinline__ float tanhf_(float x) {
    float t = __expf(-2.0f * fabsf(x));
    float r = (1.0f - t) / (1.0f + t);
    return copysignf(r, x);
}

static __device__ __forceinline__ f16x8 pack8(float4 a, float4 b) {
    f16x8 r;
    r[0] = (f16)a.x; r[1] = (f16)a.y; r[2] = (f16)a.z; r[3] = (f16)a.w;
    r[4] = (f16)b.x; r[5] = (f16)b.y; r[6] = (f16)b.z; r[7] = (f16)b.w;
    return r;
}

// ---- coherent-point (MALL) access helpers: bypass L1+L2, no cache fences ----
static __device__ __forceinline__ void store_u16_sys(void* p, unsigned short v) {
    asm volatile("global_store_short %0, %1, off sc0 sc1" :: "v"(p), "v"(v) : "memory");
}
static __device__ __forceinline__ void store_u32_sys(void* p, unsigned v) {
    asm volatile("global_store_dword %0, %1, off sc0 sc1" :: "v"(p), "v"(v) : "memory");
}
static __device__ __forceinline__ int load_i32_sys(const void* p) {
    int v;
    asm volatile("global_load_dword %0, %1, off sc0 sc1\n\ts_waitcnt vmcnt(0)"
                 : "=&v"(v) : "v"(p) : "memory");
    return v;
}
static __device__ __forceinline__ void load2x16_sys(const void* p0, const void* p1,
                                                    f32x4* a, f32x4* b) {
    asm volatile("global_load_dwordx4 %0, %2, off sc0 sc1\n\t"
                 "global_load_dwordx4 %1, %3, off sc0 sc1\n\t"
                 "s_waitcnt vmcnt(0)"
                 : "=&v"(*a), "=&v"(*b) : "v"(p0), "v"(p1) : "memory");
}
static __device__ __forceinline__ void drain_stores() {
    asm volatile("s_waitcnt vmcnt(0)" ::: "memory");
}

// ---------------- transpose: f32 in[512][2048] -> f16 out[2048][512] ----------------
__global__ __launch_bounds__(256)
void k_transpose(const float* __restrict__ in, f16* __restrict__ out) {
    __shared__ f16 tile[64][72];
    const int c0 = blockIdx.x * 64;
    const int r0 = blockIdx.y * 64;
    const int tid = threadIdx.x;
    {
        const int lr = tid >> 2;
        const int lc = (tid & 3) << 4;
        const float* src = in + (size_t)(r0 + lr) * NGATE + c0 + lc;
        float4 v0 = ((const float4*)src)[0];
        float4 v1 = ((const float4*)src)[1];
        float4 v2 = ((const float4*)src)[2];
        float4 v3 = ((const float4*)src)[3];
        *(f16x8*)&tile[lr][lc]     = pack8(v0, v1);
        *(f16x8*)&tile[lr][lc + 8] = pack8(v2, v3);
    }
    __syncthreads();
    {
        const int lc = tid >> 2;
        const int lr = (tid & 3) << 4;
        f16x8 a, b;
#pragma unroll
        for (int i = 0; i < 8; ++i) a[i] = tile[lr + i][lc];
#pragma unroll
        for (int i = 0; i < 8; ++i) b[i] = tile[lr + 8 + i][lc];
        f16* dst = out + (size_t)(c0 + lc) * NKIN + r0 + lr;
        *(f16x8*)dst       = a;
        *(f16x8*)(dst + 8) = b;
    }
}

// ---------------- projection: xz[t][b][g] = x[b][t][:] @ W[:][g] + bias[g] ----------------
__global__ __launch_bounds__(256)
void k_proj(const float* __restrict__ x, const f16* __restrict__ Wt,
            const float* __restrict__ bias, f16* __restrict__ xz) {
    __shared__ f16 As[128][40];
    __shared__ f16 Bs[128][40];
    const int bid = blockIdx.y * gridDim.x + blockIdx.x;   // 0..2047
    const int swz = (bid & 7) * 256 + (bid >> 3);          // XCD-contiguous chunks
    const int nb = swz & 15;
    const int tb = swz >> 4;
    const int n0 = nb * 128;
    const int tid  = threadIdx.x;
    const int lane = tid & 63;
    const int wid  = tid >> 6;
    const int wm = (wid >> 1) * 64;
    const int wn = (wid & 1) * 64;
    const int lm = lane & 15;
    const int lg = lane >> 4;

    f32x4 acc[4][4];
#pragma unroll
    for (int mi = 0; mi < 4; ++mi)
#pragma unroll
        for (int ni = 0; ni < 4; ++ni)
#pragma unroll
            for (int i = 0; i < 4; ++i) acc[mi][ni][i] = 0.0f;

    for (int kt = 0; kt < NKIN; kt += 32) {
        {
            const int brow = tid >> 1;
            const int kq   = (tid & 1) << 4;
            const float* src = x + ((size_t)brow * NTIME + tb) * NKIN + kt + kq;
            float4 v0 = ((const float4*)src)[0];
            float4 v1 = ((const float4*)src)[1];
            float4 v2 = ((const float4*)src)[2];
            float4 v3 = ((const float4*)src)[3];
            *(f16x8*)&As[brow][kq]     = pack8(v0, v1);
            *(f16x8*)&As[brow][kq + 8] = pack8(v2, v3);
        }
        {
            const int nrow = tid >> 1;
            const int kq   = (tid & 1) << 4;
            const f16* src = Wt + (size_t)(n0 + nrow) * NKIN + kt + kq;
            *(f16x8*)&Bs[nrow][kq]     = *(const f16x8*)src;
            *(f16x8*)&Bs[nrow][kq + 8] = *(const f16x8*)(src + 8);
        }
        __syncthreads();
        f16x8 a[4], b[4];
#pragma unroll
        for (int mi = 0; mi < 4; ++mi)
            a[mi] = *(const f16x8*)&As[wm + mi * 16 + lm][lg * 8];
#pragma unroll
        for (int ni = 0; ni < 4; ++ni)
            b[ni] = *(const f16x8*)&Bs[wn + ni * 16 + lm][lg * 8];
#pragma unroll
        for (int mi = 0; mi < 4; ++mi)
#pragma unroll
            for (int ni = 0; ni < 4; ++ni)
                acc[mi][ni] = __builtin_amdgcn_mfma_f32_16x16x32_f16(a[mi], b[ni], acc[mi][ni], 0, 0, 0);
        __syncthreads();
    }
#pragma unroll
    for (int mi = 0; mi < 4; ++mi) {
#pragma unroll
        for (int ni = 0; ni < 4; ++ni) {
            const int col = n0 + wn + ni * 16 + lm;
            const float bv = bias[col];
#pragma unroll
            for (int i = 0; i < 4; ++i) {
                const int brow = wm + mi * 16 + lg * 4 + i;
                xz[((size_t)tb * NBATCH + brow) * NGATE + col] = (f16)(acc[mi][ni][i] + bv);
            }
        }
    }
}

// ---------------- persistent LSTM ----------------
// 256 blocks = 16 groups x 16 blocks. Group = 8 batch rows; block = 32 unit-cols
// (x4 gates = 128 gate-cols, 128KB U-slice in LDS). h + flags exchanged via
// sc0sc1 (MALL-coherent) ops; NO acquire/release fences -> L2 stays warm for xz.
__global__ __launch_bounds__(256)
void k_lstm(const f16* __restrict__ xz, const f16* __restrict__ Ut,
            f16* __restrict__ h0, f16* __restrict__ h1,
            float* __restrict__ out, int* __restrict__ flags) {
    __shared__ f16 Us[128][512];     // 128 local gate-cols x 512 k, XOR-swizzled
    __shared__ f16 As[16][512];      // h rows (8 valid + 8 zero), XOR-swizzled
    __shared__ float zs[4][GROWS][33];
    const int bid = blockIdx.x;
    const int grp = bid & 15;
    const int ug  = bid >> 4;
    const int r0 = grp * GROWS;
    const int u0 = ug * 32;
    const int tid  = threadIdx.x;
    const int lane = tid & 63;
    const int g    = tid >> 6;       // wave id == gate
    const int lm = lane & 15;
    const int lg = lane >> 4;

    // one-time: stage U-slice (swizzled). 8192 chunks of 8 f16; 32 per thread.
#pragma unroll
    for (int i = 0; i < 32; ++i) {
        const int idx = tid + i * 256;
        const int c   = idx >> 6;           // local col 0..127
        const int ck  = idx & 63;           // chunk 0..63
        const int gcol = (c >> 5) * NUNITS + u0 + (c & 31);
        f16x8 v = *(const f16x8*)(Ut + (size_t)gcol * NUNITS + ck * 8);
        *(f16x8*)&Us[c][(ck ^ (c & 7)) * 8] = v;
    }
    // zero As rows 8..15 (M=16 MFMA, only 8 valid rows)
    {
        f32x4 z = {0.f, 0.f, 0.f, 0.f};
        for (int i = tid; i < 8 * 64; i += 256) {
            const int r = 8 + (i >> 6);
            *(f32x4*)&As[r][(i & 63) * 8] = z;
        }
    }

    const int srow = tid >> 5;       // 0..7
    const int suu  = tid & 31;       // 0..31
    const int gidx = (r0 + srow) * NUNITS + u0 + suu;
    int* gf = flags + grp * BLKPG;
    float c_reg = 0.0f;

    // xz prefetch registers (t=0)
    float px[8] = {0.f, 0.f, 0.f, 0.f, 0.f, 0.f, 0.f, 0.f};
    if (lg < 2) {
        const f16* xp = xz + ((size_t)(r0 + lg * 4)) * NGATE + g * NUNITS + u0 + lm;
#pragma unroll
        for (int i = 0; i < 4; ++i) {
            px[i]     = (float)xp[(size_t)i * NGATE];
            px[4 + i] = (float)xp[(size_t)i * NGATE + 16];
        }
    }

    for (int t = 0; t < NTIME; ++t) {
        const f16* hin = (t & 1) ? h1 : h0;
        f16*      hout = (t & 1) ? h0 : h1;

        // wait for h[t-1]: all group flags >= t (monotonic counters)
        if (t > 0) {
            const int* myf = gf + (lane & 15);
            for (;;) {
                int v = load_i32_sys(myf);
                if (__all(v >= t)) break;
                __builtin_amdgcn_s_sleep(1);
            }
        }
        // stage h rows (8 x 512 f16 = 8KB) via MALL-coherent loads
        {
            const int row = tid >> 5;
            const int c0_ = tid & 31;
            const f16* src = hin + (size_t)(r0 + row) * NUNITS;
            f32x4 a, b;
            load2x16_sys(src + c0_ * 8, src + (c0_ + 32) * 8, &a, &b);
            *(f32x4*)&As[row][(c0_ ^ (row & 7)) * 8]        = a;
            *(f32x4*)&As[row][((c0_ + 32) ^ (row & 7)) * 8] = b;
        }
        __syncthreads();

        f32x4 acc0, acc1;
#pragma unroll
        for (int i = 0; i < 4; ++i) { acc0[i] = px[i]; acc1[i] = px[4 + i]; }

#pragma unroll
        for (int ks = 0; ks < 16; ++ks) {
            const int ca = ((ks * 4 + lg) ^ (lm & 7)) * 8;
            f16x8 a  = *(const f16x8*)&As[lm][ca];
            f16x8 b0 = *(const f16x8*)&Us[g * 32 + lm][ca];
            f16x8 b1 = *(const f16x8*)&Us[g * 32 + 16 + lm][ca];
            acc0 = __builtin_amdgcn_mfma_f32_16x16x32_f16(a, b0, acc0, 0, 0, 0);
            acc1 = __builtin_amdgcn_mfma_f32_16x16x32_f16(a, b1, acc1, 0, 0, 0);
        }

        // prefetch next step's xz (independent of barrier; L2-warm)
        {
            const int tn = (t + 1 < NTIME) ? t + 1 : t;
            if (lg < 2) {
                const f16* xp = xz + ((size_t)tn * NBATCH + r0 + lg * 4) * NGATE
                                   + g * NUNITS + u0 + lm;
#pragma unroll
                for (int i = 0; i < 4; ++i) {
                    px[i]     = (float)xp[(size_t)i * NGATE];
                    px[4 + i] = (float)xp[(size_t)i * NGATE + 16];
                }
            }
        }

        // gate exchange
        if (lg < 2) {
#pragma unroll
            for (int i = 0; i < 4; ++i) {
                zs[g][lg * 4 + i][lm]      = acc0[i];
                zs[g][lg * 4 + i][16 + lm] = acc1[i];
            }
        }
        __syncthreads();

        // state update: 256 threads = 8 rows x 32 units
        const float zi = zs[0][srow][suu];
        const float zf = zs[1][srow][suu];
        const float zg = zs[2][srow][suu];
        const float zo = zs[3][srow][suu];
        const float iv = sigmoidf_(zi);
        const float fv = sigmoidf_(zf);
        const float gv = tanhf_(zg);
        const float ov = sigmoidf_(zo);
        c_reg = fv * c_reg + iv * gv;
        const float hn = ov * tanhf_(c_reg);

        if (t == NTIME - 1) {
            out[gidx]          = hn;
            out[65536 + gidx]  = hn;
            out[131072 + gidx] = c_reg;
        } else {
            union { f16 h; unsigned short u; } cv; cv.h = (f16)hn;
            store_u16_sys(hout + gidx, cv.u);
            drain_stores();          // per-wave: h stores visible at MALL
            __syncthreads();         // all waves drained
            if (tid == 0) store_u32_sys(gf + ug, t + 1);
        }
    }
}

extern "C" void kernel_launch(void* const* d_in, const int* in_sizes, int n_in,
                              void* d_out, int out_size, void* d_ws, size_t ws_size,
                              hipStream_t stream) {
    const float* x    = (const float*)d_in[0];
    const float* W    = (const float*)d_in[1];
    const float* U    = (const float*)d_in[2];
    const float* bias = (const float*)d_in[3];
    float* out = (float*)d_out;
    char* ws = (char*)d_ws;

    size_t off = 0;
    f16* Wt = (f16*)(ws + off); off += (size_t)NGATE * NKIN * 2;
    f16* Ut = (f16*)(ws + off); off += (size_t)NGATE * NUNITS * 2;
    f16* xz = (f16*)(ws + off); off += (size_t)NTIME * NBATCH * NGATE * 2;  // [t][b][g]
    f16* h0 = (f16*)(ws + off); off += (size_t)NBATCH * NUNITS * 2;
    f16* h1 = (f16*)(ws + off); off += (size_t)NBATCH * NUNITS * 2;
    int* flags = (int*)(ws + off); off += GROUPS * BLKPG * sizeof(int);
    if (ws_size < off) return;

    hipMemsetAsync(h0,    0, (size_t)NBATCH * NUNITS * 2, stream);
    hipMemsetAsync(flags, 0, GROUPS * BLKPG * sizeof(int), stream);

    k_transpose<<<dim3(32, 8), 256, 0, stream>>>(W, Wt);
    k_transpose<<<dim3(32, 8), 256, 0, stream>>>(U, Ut);
    k_proj<<<dim3(16, 128), 256, 0, stream>>>(x, Wt, bias, xz);
    k_lstm<<<dim3(256), 256, 0, stream>>>(xz, Ut, h0, h1, out, flags);
}